// Round 2
// baseline (331.742 us; speedup 1.0000x reference)
//
#include <hip/hip_runtime.h>

// CTC forward loss, B=256, T=1024, C=128, L=64, S=2L+1=129, BLANK=127.
// One wave per batch element. Lane i owns states 2i (blank) and 2i+1 (label i);
// lane 63 also owns state 128 (trailing blank). All math in log2 domain so
// v_exp_f32 / v_log_f32 are used natively; convert by ln2 at the end.

#define B_    256
#define T_    1024
#define C_    128
#define L_    64
#define BLANK_ 127
#define EPS_  1e-7f
#define NEG_  -1e30f
#define PF    8     // prefetch depth (register ring buffer, fully unrolled)
#define LN2_  0.69314718055994530942f

// glibc math.h reserves __exp2f/__log2f for host — use the amdgcn builtins.
__device__ __forceinline__ float fexp2(float x) {
#if __has_builtin(__builtin_amdgcn_exp2f)
    return __builtin_amdgcn_exp2f(x);   // v_exp_f32: 2^x
#else
    return exp2f(x);
#endif
}
__device__ __forceinline__ float flog2(float x) {
#if __has_builtin(__builtin_amdgcn_logf)
    return __builtin_amdgcn_logf(x);    // v_log_f32: log2(x)
#else
    return log2f(x);
#endif
}

__global__ __launch_bounds__(64, 1)
void ctc_fwd(const int* __restrict__ yt, const float* __restrict__ yp,
             float* __restrict__ out) {
    const int b    = blockIdx.x;
    const int lane = threadIdx.x;            // 0..63
    const int lab  = yt[b * L_ + lane];      // label owned by this lane (state 2i+1)
    const int labp = __shfl_up(lab, 1);
    const bool can_skip = (lane > 0) && (lab != labp);  // ext[2i+1]!=ext[2i-1]

    const float* __restrict__ base = yp + (size_t)b * T_ * C_;

    // ---- prefetch ring: slots hold times t=1..PF initially ----
    float bufL[PF], bufB[PF];
#pragma unroll
    for (int k = 0; k < PF; ++k) {
        bufL[k] = base[(size_t)(1 + k) * C_ + lab];
        bufB[k] = base[(size_t)(1 + k) * C_ + BLANK_];
    }

    // ---- t = 0 init: only s=0 and s=1 reachable ----
    const float p0L = base[lab];
    const float p0B = base[BLANK_];
    float aE = (lane == 0) ? flog2(p0B + EPS_) : NEG_;  // state 2i
    float aO = (lane == 0) ? flog2(p0L + EPS_) : NEG_;  // state 2i+1
    float aX = NEG_;                                    // state 128 (lane 63)

    int t = 1;
    // (T_-1) = 1023 = 127*PF + 7
#pragma unroll 1
    for (int chunk = 0; chunk < (T_ - 1) / PF; ++chunk) {
#pragma unroll
        for (int k = 0; k < PF; ++k, ++t) {
            const float pL = bufL[k];
            const float pB = bufB[k];
            // prefetch t+PF (clamped; duplicate loads at the tail are harmless)
            int tt = t + PF; tt = (tt > T_ - 1) ? (T_ - 1) : tt;
            bufL[k] = base[(size_t)tt * C_ + lab];
            bufB[k] = base[(size_t)tt * C_ + BLANK_];

            const float lpB = flog2(pB + EPS_);
            const float lpL = flog2(pL + EPS_);

            // previous-iteration neighbor: alpha[2i-1] lives in lane i-1's aO
            float prevO = __shfl_up(aO, 1);
            if (lane == 0) prevO = NEG_;

            // state 2i (blank): LSE2(alpha[2i], alpha[2i-1]) + lpB
            const float m1 = fmaxf(aE, prevO);
            const float nE = m1 + flog2(fexp2(aE - m1) + fexp2(prevO - m1)) + lpB;

            // state 2i+1 (label): LSE3(alpha[2i+1], alpha[2i], skip?alpha[2i-1]) + lpL
            const float sk = can_skip ? prevO : NEG_;
            const float m2 = fmaxf(fmaxf(aO, aE), sk);
            const float nO = m2 + flog2(fexp2(aO - m2) + fexp2(aE - m2) +
                                        fexp2(sk - m2)) + lpL;

            // state 128 (blank): LSE2(alpha[128], alpha[127]) + lpB
            // (computed on all lanes; only lane 63's values are meaningful)
            const float m3 = fmaxf(aX, aO);
            const float nX = m3 + flog2(fexp2(aX - m3) + fexp2(aO - m3)) + lpB;

            aE = nE; aO = nO; aX = nX;
        }
    }
    // remainder: 7 iterations, no prefetch needed (ring already holds them)
#pragma unroll
    for (int k = 0; k < (T_ - 1) % PF; ++k, ++t) {
        const float pL = bufL[k];
        const float pB = bufB[k];

        const float lpB = flog2(pB + EPS_);
        const float lpL = flog2(pL + EPS_);

        float prevO = __shfl_up(aO, 1);
        if (lane == 0) prevO = NEG_;

        const float m1 = fmaxf(aE, prevO);
        const float nE = m1 + flog2(fexp2(aE - m1) + fexp2(prevO - m1)) + lpB;

        const float sk = can_skip ? prevO : NEG_;
        const float m2 = fmaxf(fmaxf(aO, aE), sk);
        const float nO = m2 + flog2(fexp2(aO - m2) + fexp2(aE - m2) +
                                    fexp2(sk - m2)) + lpL;

        const float m3 = fmaxf(aX, aO);
        const float nX = m3 + flog2(fexp2(aX - m3) + fexp2(aO - m3)) + lpB;

        aE = nE; aO = nO; aX = nX;
    }

    // log_lik = logaddexp(alpha[128], alpha[127]); loss = -log_lik (natural log)
    if (lane == 63) {
        const float m = fmaxf(aX, aO);
        const float ll2 = m + flog2(fexp2(aX - m) + fexp2(aO - m));
        out[b] = -ll2 * LN2_;
    }
}

extern "C" void kernel_launch(void* const* d_in, const int* in_sizes, int n_in,
                              void* d_out, int out_size, void* d_ws, size_t ws_size,
                              hipStream_t stream) {
    const int*   y_true = (const int*)d_in[0];
    const float* y_pred = (const float*)d_in[1];
    float*       out    = (float*)d_out;
    ctc_fwd<<<B_, 64, 0, stream>>>(y_true, y_pred, out);
}

// Round 3
// 255.634 us; speedup vs baseline: 1.2977x; 1.2977x over previous
//
#include <hip/hip_runtime.h>

// CTC forward loss, B=256, T=1024, C=128, L=64, S=2L+1=129, BLANK=127.
// One wave per batch element (256 blocks x 64 threads = 1 wave/CU).
//
// State layout (round 2): lane i owns state 2i+1 (label y[i], reg aO) and
// state 2i+2 (blank, reg aE). State 0 is a scalar self-loop chain a0 += lpB
// (no LSE), replicated in all lanes. Consequences:
//   - blank update nE = LSE2(aE, aO) + lpB is lane-LOCAL (no cross-lane)
//   - label update nO = LSE3(aO, prevE, can_skip ? prevO : NEG) + lpL needs
//     two neighbor values, fetched with DPP wave_ror:1 (~2 cyc, no LDS path)
//   - final states 127 (aO) and 128 (aE) both live in lane 63 -> local finish
// All math in log2 domain (v_exp_f32 / v_log_f32 native); convert by ln2 at end.

#define B_     256
#define T_     1024
#define C_     128
#define L_     64
#define BLANK_ 127
#define EPS_   1e-7f
#define NEG_   -1e30f
#define PF     16    // prefetch ring depth (2 loads/step, 32 in flight)
#define LN2_   0.69314718055994530942f

// glibc math.h reserves __exp2f/__log2f for host - use amdgcn builtins.
__device__ __forceinline__ float fexp2(float x) { return __builtin_amdgcn_exp2f(x); }
__device__ __forceinline__ float flog2(float x) { return __builtin_amdgcn_logf(x); }

// whole-wave rotate-right-by-1 via DPP (gfx9-family wave_ror:1 = 0x13C):
// lane i receives src from lane (i-1)&63. ~2 cycles, stays in the VALU.
__device__ __forceinline__ float ror1(float x) {
    int xi = __float_as_int(x);
    int r  = __builtin_amdgcn_update_dpp(xi, xi, 0x13C, 0xF, 0xF, false);
    return __int_as_float(r);
}

// One DP step. Consumes emission probs (pL: this lane's label col, pB: blank
// col), updates a0/aE/aO in place.
#define STEP(pL, pB)                                                          \
    {                                                                         \
        const float lpB = flog2((pB) + EPS_);                                 \
        const float lpL = flog2((pL) + EPS_);                                 \
        float prevE = ror1(aE);                                               \
        float prevO = ror1(aO);                                               \
        prevE = isL0 ? a0 : prevE;      /* lane0: pred of state1 is state0 */ \
        const float sk = can_skip ? prevO : NEG_;                             \
        a0 += lpB;                      /* state 0: pure self-loop */         \
        /* nE = LSE2(aE, aO) + lpB  (lane-local), -|d| single-exp form */     \
        const float d  = aE - aO;                                             \
        const float nd = fminf(d, -d);                                        \
        const float nE = fmaxf(aE, aO) + flog2(1.0f + fexp2(nd)) + lpB;       \
        /* nO = LSE3(aO, prevE, sk) + lpL */                                  \
        const float m2 = fmaxf(fmaxf(aO, prevE), sk);                         \
        const float nO = m2 + flog2(fexp2(aO - m2) + fexp2(prevE - m2) +      \
                                    fexp2(sk - m2)) + lpL;                    \
        aE = nE; aO = nO;                                                     \
    }

__global__ __launch_bounds__(64, 1)
void ctc_fwd(const int* __restrict__ yt, const float* __restrict__ yp,
             float* __restrict__ out) {
    const int b    = blockIdx.x;
    const int lane = threadIdx.x;                 // 0..63
    const int lab  = yt[b * L_ + lane];           // label of state 2*lane+1
    const int labp = __shfl_up(lab, 1);           // init-only, off hot path
    const bool can_skip = (lane > 0) && (lab != labp);
    const bool isL0     = (lane == 0);

    const float* __restrict__ base = yp + (size_t)b * T_ * C_;

    // prefetch ring: rows t = 1..PF
    float bufL[PF], bufB[PF];
    const float* p = base + C_;
#pragma unroll
    for (int k = 0; k < PF; ++k) {
        bufL[k] = p[k * C_ + lab];
        bufB[k] = p[k * C_ + BLANK_];             // uniform addr -> SMEM-able
    }

    // t = 0 init: only states 0 and 1 reachable
    float a0 = flog2(base[BLANK_] + EPS_);        // state 0 (uniform scalar)
    float aO = isL0 ? flog2(base[lab] + EPS_) : NEG_;  // state 2i+1
    float aE = NEG_;                              // state 2i+2

    // main: 62 chunks x PF steps -> t = 1..992; refills reach t=1008 (<T) so
    // no prefetch ever goes out of bounds.
#pragma unroll 1
    for (int c = 0; c < 62; ++c) {
#pragma unroll
        for (int k = 0; k < PF; ++k) {
            const float pL = bufL[k];
            const float pB = bufB[k];
            bufL[k] = p[(k + PF) * C_ + lab];
            bufB[k] = p[(k + PF) * C_ + BLANK_];
            STEP(pL, pB)
        }
        p += PF * C_;
    }
    // phase A: t = 993..1008; refill slots 0..14 with rows 1009..1023
#pragma unroll
    for (int k = 0; k < PF; ++k) {
        const float pL = bufL[k];
        const float pB = bufB[k];
        if (k < PF - 1) {
            bufL[k] = p[(k + PF) * C_ + lab];
            bufB[k] = p[(k + PF) * C_ + BLANK_];
        }
        STEP(pL, pB)
    }
    // phase B: t = 1009..1023 from slots 0..14, no refill
#pragma unroll
    for (int k = 0; k < PF - 1; ++k) {
        STEP(bufL[k], bufB[k])
    }

    // loss = -ln( exp(alpha[127]) + exp(alpha[128]) ); both live in lane 63
    if (lane == 63) {
        const float m   = fmaxf(aE, aO);
        const float ll2 = m + flog2(fexp2(aE - m) + fexp2(aO - m));
        out[b] = -ll2 * LN2_;
    }
}

extern "C" void kernel_launch(void* const* d_in, const int* in_sizes, int n_in,
                              void* d_out, int out_size, void* d_ws, size_t ws_size,
                              hipStream_t stream) {
    const int*   y_true = (const int*)d_in[0];
    const float* y_pred = (const float*)d_in[1];
    float*       out    = (float*)d_out;
    ctc_fwd<<<B_, 64, 0, stream>>>(y_true, y_pred, out);
}

// Round 7
// 252.486 us; speedup vs baseline: 1.3139x; 1.0125x over previous
//
#include <hip/hip_runtime.h>

// CTC forward loss, B=256, T=1024, C=128, L=64, S=2L+1=129, BLANK=127.
// One wave per batch element (256 blocks x 64 threads).
//
// LINEAR-domain recursion, per-lane exponent, renormalized EVERY step:
//   a'[s] = (a[s] + a[s-1] + can_skip*a[s-2]) * (p[s]+eps)
// Lane i holds states 2i+1 (label, aO) and 2i+2 (blank, aE) as f32 mantissas
// with max(aE,aO) in [1,2), plus int exponent e (true alpha = m * 2^e).
// Neighbor alignment: prev = v_ldexp(m_{i-1}, e_{i-1} - e_i) -- ldexp(0,n)=0,
// so no inf "factor" ever enters live math (round-5's bug). Dead lanes
// (local max == 0) adopt the neighbor's exponent each step, so the exponent
// field tracks the advancing front (1 lane/step) and incoming mass is never
// flushed by a stale scale. Bounds: within-lane aE >= 2^-24 * lane_max ->
// adjacent-lane exponent gap <= ~49 -> all shifts finite; per-step shrink
// >= 2^-24 -> per-step renorm never underflows. Zero transcendentals on the
// 1023-step chain. State 0 is a wave-uniform chain (a0, e0), entering only
// lane 0's update via ldexp(a0, e0 - e).

#define B_     256
#define T_     1024
#define C_     128
#define L_     64
#define BLANK_ 127
#define EPS_   1e-7f
#define PF     16    // prefetch ring depth (2 loads/step, 32 in flight)
#define LN2_   0.69314718055994530942f

__device__ __forceinline__ float flog2(float x) { return __builtin_amdgcn_logf(x); }

template <int CTRL>
__device__ __forceinline__ int dpp_i(int x) {
    return __builtin_amdgcn_update_dpp(x, x, CTRL, 0xF, 0xF, false);
}
// whole-wave rotate: lane i receives lane (i-1)&63 (verified empirically in R2)
__device__ __forceinline__ float ror1_f(float x) {
    return __int_as_float(dpp_i<0x13C>(__float_as_int(x)));
}
__device__ __forceinline__ int ror1_i(int x) { return dpp_i<0x13C>(x); }

__device__ __forceinline__ float fldexp(float x, int n) {
#if __has_builtin(__builtin_amdgcn_ldexpf)
    return __builtin_amdgcn_ldexpf(x, n);
#else
    return ldexpf(x, n);
#endif
}

// One DP step + per-step renorm (~30 cheap VALU, no transcendentals).
// Lane 0: raw prevE/prevO may be huge/inf from the lane-63 wraparound, but
// prevE is cndmask-replaced by the state-0 term and prevO is gated off by
// can_skip=false, so garbage never enters live arithmetic.
#define LSTEP(pL, pB)                                                         \
    {                                                                         \
        const float pBe = (pB) + EPS_;                                        \
        const float pLe = (pL) + EPS_;                                        \
        const int   ep  = ror1_i(e);                                          \
        const float mpE = ror1_f(aE);                                         \
        const float mpO = ror1_f(aO);                                         \
        const int   d   = ep - e;                                             \
        float prevE = fldexp(mpE, d);                                         \
        const float prevO = fldexp(mpO, d);                                   \
        prevE = isL0 ? fldexp(a0, e0 - e) : prevE;                            \
        const float sk = can_skip ? prevO : 0.0f;                             \
        const float nE = (aE + aO) * pBe;                                     \
        const float nO = (aO + prevE + sk) * pLe;                             \
        /* state-0 chain (a0 > 0 always; renorm unconditionally) */           \
        a0 *= pBe;                                                            \
        const int x0 = (__float_as_int(a0) >> 23) - 127;                      \
        a0 = fldexp(a0, -x0);                                                 \
        e0 += x0;                                                             \
        /* per-step renorm; lm==0 -> x=-127, ldexp(0,127)=0, adopt ep */      \
        const float lm = fmaxf(nE, nO);                                       \
        const int x = (__float_as_int(lm) >> 23) - 127;                       \
        aE = fldexp(nE, -x);                                                  \
        aO = fldexp(nO, -x);                                                  \
        e = (lm > 0.0f) ? (e + x) : ep;                                       \
    }

__global__ __launch_bounds__(64, 1)
void ctc_fwd(const int* __restrict__ yt, const float* __restrict__ yp,
             float* __restrict__ out) {
    const int b    = blockIdx.x;
    const int lane = threadIdx.x;                 // 0..63
    const int lab  = yt[b * L_ + lane];           // label of state 2*lane+1
    const int labp = __shfl_up(lab, 1);           // init-only, off hot path
    const bool can_skip = (lane > 0) && (lab != labp);
    const bool isL0     = (lane == 0);

    const float* __restrict__ base = yp + (size_t)b * T_ * C_;

    // prefetch ring: rows t = 1..PF
    float bufL[PF], bufB[PF];
    const float* p = base + C_;
#pragma unroll
    for (int k = 0; k < PF; ++k) {
        bufL[k] = p[k * C_ + lab];
        bufB[k] = p[k * C_ + BLANK_];             // wave-uniform address
    }

    // t=0 init (linear, exponent 0): only states 0 and 1 reachable.
    float a0 = base[BLANK_] + EPS_;               // state 0 (uniform)
    float aO = isL0 ? (base[lab] + EPS_) : 0.0f;  // state 2i+1
    float aE = 0.0f;                              // state 2i+2
    int   e  = 0, e0 = 0;                         // per-lane / state-0 exponents

    // main: 62 chunks x 16 steps -> t = 1..992; refills stay <= row 1008.
#pragma unroll 1
    for (int c = 0; c < 62; ++c) {
#pragma unroll
        for (int k = 0; k < PF; ++k) {
            const float pL = bufL[k];
            const float pB = bufB[k];
            bufL[k] = p[(k + PF) * C_ + lab];
            bufB[k] = p[(k + PF) * C_ + BLANK_];
            LSTEP(pL, pB)
        }
        p += PF * C_;
    }
    // phase A: t = 993..1008; refill slots k<15 with rows 1009..1023.
#pragma unroll
    for (int k = 0; k < PF; ++k) {
        const float pL = bufL[k];
        const float pB = bufB[k];
        if (k < PF - 1) {
            bufL[k] = p[(k + PF) * C_ + lab];
            bufB[k] = p[(k + PF) * C_ + BLANK_];
        }
        LSTEP(pL, pB)
    }
    // phase B: t = 1009..1023 (15 steps) from slots 0..14.
#pragma unroll
    for (int k = 0; k < PF - 1; ++k) {
        LSTEP(bufL[k], bufB[k])
    }

    // loss = -ln(alpha[127] + alpha[128]); both live in lane 63 at scale 2^e.
    if (lane == 63) {
        float s = aE + aO;                        // in [2^-24, 4): log2 is safe
        out[b] = -(flog2(s) + (float)e) * LN2_;
    }
}

extern "C" void kernel_launch(void* const* d_in, const int* in_sizes, int n_in,
                              void* d_out, int out_size, void* d_ws, size_t ws_size,
                              hipStream_t stream) {
    const int*   y_true = (const int*)d_in[0];
    const float* y_pred = (const float*)d_in[1];
    float*       out    = (float*)d_out;
    ctc_fwd<<<B_, 64, 0, stream>>>(y_true, y_pred, out);
}

// Round 8
// 249.039 us; speedup vs baseline: 1.3321x; 1.0138x over previous
//
#include <hip/hip_runtime.h>

// CTC forward loss, B=256, T=1024, C=128, L=64, S=2L+1=129, BLANK=127.
// One wave per batch element (256 blocks x 64 threads).
//
// LINEAR-domain recursion, per-lane exponent:
//   a'[s] = (a[s] + a[s-1] + can_skip*a[s-2]) * (p[s]+eps)
// Lane i holds states 2i+1 (label, aO) and 2i+2 (blank, aE) as f32 mantissas
// plus int exponent e (true alpha = m * 2^e). Renorm every 4 steps (shrink
// >= pmin^4 = 2^-68: no underflow; growth <= 6^4: no overflow). Neighbor
// alignment via v_ldexp(m_{i-1}, e_{i-1}-e_i): ldexp of 0 is 0 for any
// shift, so no inf enters live math. Front handling is per-step but cheap:
// a dead lane (max==0) adopts the neighbor's exponent, making its shift d=0
// exactly when mass first arrives -- the DP front is never flushed.
// Zero transcendentals on the 1023-step chain. State 0 is a wave-uniform
// chain (a0, e0), feeding lane 0's update via ldexp(a0, e0-e).

#define B_     256
#define T_     1024
#define C_     128
#define L_     64
#define BLANK_ 127
#define EPS_   1e-7f
#define PF     16    // prefetch ring depth (2 loads/step, 32 in flight)
#define LN2_   0.69314718055994530942f

__device__ __forceinline__ float flog2(float x) { return __builtin_amdgcn_logf(x); }

template <int CTRL>
__device__ __forceinline__ int dpp_i(int x) {
    return __builtin_amdgcn_update_dpp(x, x, CTRL, 0xF, 0xF, false);
}
// whole-wave rotate: lane i receives lane (i-1)&63
__device__ __forceinline__ float ror1_f(float x) {
    return __int_as_float(dpp_i<0x13C>(__float_as_int(x)));
}
__device__ __forceinline__ int ror1_i(int x) { return dpp_i<0x13C>(x); }

__device__ __forceinline__ float fldexp(float x, int n) {
#if __has_builtin(__builtin_amdgcn_ldexpf)
    return __builtin_amdgcn_ldexpf(x, n);
#else
    return ldexpf(x, n);
#endif
}
// exponent such that ldexp(x, -fexp_of(x)) is in [0.5,1); returns 0 for x==0
__device__ __forceinline__ int fexp_of(float x) {
#if __has_builtin(__builtin_amdgcn_frexp_expf)
    return __builtin_amdgcn_frexp_expf(x);
#else
    const int bx = (__float_as_int(x) >> 23) & 0xFF;
    return (x > 0.0f) ? (bx - 126) : 0;
#endif
}

// One DP step (~24 VALU, no transcendentals, no renorm).
// Lane 0: raw prevE/prevO can be garbage from the lane-63 wraparound, but
// prevE is cndmask-replaced by the state-0 term and prevO is gated off by
// can_skip=false; ldexp never produces inf from a zero mantissa.
#define LSTEP(pL, pB)                                                         \
    {                                                                         \
        const float pBe = (pB) + EPS_;                                        \
        const float pLe = (pL) + EPS_;                                        \
        const int   ep  = ror1_i(e);                                          \
        const float mpE = ror1_f(aE);                                         \
        const float mpO = ror1_f(aO);                                         \
        const bool dead = (fmaxf(aE, aO) == 0.0f);                            \
        e = dead ? ep : e;               /* dead lanes track the front */     \
        const int   d   = ep - e;        /* == 0 when mass first arrives */   \
        float prevE = fldexp(mpE, d);                                         \
        const float prevO = fldexp(mpO, d);                                   \
        prevE = isL0 ? fldexp(a0, e0 - e) : prevE;                            \
        const float sk = can_skip ? prevO : 0.0f;                             \
        const float nE = (aE + aO) * pBe;                                     \
        const float nO = (aO + prevE + sk) * pLe;                             \
        a0 *= pBe;                                                            \
        aE = nE; aO = nO;                                                     \
    }

// Renorm (every 4 steps). frexp_exp(0)=0 so dead lanes are a no-op.
#define RENORM4                                                               \
    {                                                                         \
        const int x = fexp_of(fmaxf(aE, aO));                                 \
        aE = fldexp(aE, -x); aO = fldexp(aO, -x); e += x;                     \
        const int x0 = fexp_of(a0);                                           \
        a0 = fldexp(a0, -x0); e0 += x0;                                       \
    }

__global__ __launch_bounds__(64, 1)
void ctc_fwd(const int* __restrict__ yt, const float* __restrict__ yp,
             float* __restrict__ out) {
    const int b    = blockIdx.x;
    const int lane = threadIdx.x;                 // 0..63
    const int lab  = yt[b * L_ + lane];           // label of state 2*lane+1
    const int labp = __shfl_up(lab, 1);           // init-only, off hot path
    const bool can_skip = (lane > 0) && (lab != labp);
    const bool isL0     = (lane == 0);

    const float* __restrict__ base = yp + (size_t)b * T_ * C_;

    // prefetch ring: rows t = 1..PF
    float bufL[PF], bufB[PF];
    const float* p = base + C_;
#pragma unroll
    for (int k = 0; k < PF; ++k) {
        bufL[k] = p[k * C_ + lab];
        bufB[k] = p[k * C_ + BLANK_];             // wave-uniform address
    }

    // t=0 init (linear, exponent 0): only states 0 and 1 reachable.
    float a0 = base[BLANK_] + EPS_;               // state 0 (uniform)
    float aO = isL0 ? (base[lab] + EPS_) : 0.0f;  // state 2i+1
    float aE = 0.0f;                              // state 2i+2
    int   e  = 0, e0 = 0;                         // per-lane / state-0 exponents

    // main: 62 chunks x 16 steps -> t = 1..992; refills stay <= row 1008.
#pragma unroll 1
    for (int c = 0; c < 62; ++c) {
#pragma unroll
        for (int k = 0; k < PF; ++k) {
            const float pL = bufL[k];
            const float pB = bufB[k];
            bufL[k] = p[(k + PF) * C_ + lab];
            bufB[k] = p[(k + PF) * C_ + BLANK_];
            LSTEP(pL, pB)
            if ((k & 3) == 3) RENORM4
        }
        p += PF * C_;
    }
    // phase A: t = 993..1008; refill slots k<15 with rows 1009..1023.
#pragma unroll
    for (int k = 0; k < PF; ++k) {
        const float pL = bufL[k];
        const float pB = bufB[k];
        if (k < PF - 1) {
            bufL[k] = p[(k + PF) * C_ + lab];
            bufB[k] = p[(k + PF) * C_ + BLANK_];
        }
        LSTEP(pL, pB)
        if ((k & 3) == 3) RENORM4
    }
    // phase B: t = 1009..1023 (15 steps) from slots 0..14.
#pragma unroll
    for (int k = 0; k < PF - 1; ++k) {
        LSTEP(bufL[k], bufB[k])
        if ((k & 3) == 3) RENORM4   // k=3,7,11; last 3 steps un-renormed (safe)
    }

    // loss = -ln(alpha[127] + alpha[128]); both live in lane 63 at scale 2^e.
    if (lane == 63) {
        const float s = aE + aO;      // in [2^-70, 8): v_log is safe
        out[b] = -(flog2(s) + (float)e) * LN2_;
    }
}

extern "C" void kernel_launch(void* const* d_in, const int* in_sizes, int n_in,
                              void* d_out, int out_size, void* d_ws, size_t ws_size,
                              hipStream_t stream) {
    const int*   y_true = (const int*)d_in[0];
    const float* y_pred = (const float*)d_in[1];
    float*       out    = (float*)d_out;
    ctc_fwd<<<B_, 64, 0, stream>>>(y_true, y_pred, out);
}

// Round 9
// 210.551 us; speedup vs baseline: 1.5756x; 1.1828x over previous
//
#include <hip/hip_runtime.h>

// CTC forward loss, B=256, T=1024, C=128, L=64, S=2L+1=129, BLANK=127.
// One wave per batch element (256 blocks x 64 threads).
//
// Round-8 structure: the DP math (linear domain, per-lane exponent, verified
// absmax 0.0 in rounds 6/7) is unchanged. The memory path is rebuilt:
// R2-R7 did 2 global gathers per step; profiling showed ~257 cyc/step pinned
// regardless of VALU count == one memory round-trip per step (the compiler
// drains vmcnt each step; register prefetch rings don't pipeline). Now:
//   - 32 rows (16 KB) bulk-staged into double-buffered LDS via
//     global_load_lds width=16 (16 instrs/chunk, no VGPR round trip),
//   - ONE s_waitcnt vmcnt(0) per 32 steps (inline asm, memory clobber),
//   - hot loop reads 2 floats/step from LDS (blank col = uniform broadcast),
//     4-deep register ring hides ds_read latency; compiler emits fine
//     lgkmcnt for LDS->VALU (guide §5).
// Staging latency (~900 cyc) hides behind 28 steps of compute before the
// buffer swap.

#define B_     256
#define T_     1024
#define C_     128
#define L_     64
#define BLANK_ 127
#define EPS_   1e-7f
#define LN2_   0.69314718055994530942f
#define ROWS   32
#define LDSF   (ROWS * C_)      // 4096 floats = 16 KB per buffer

__device__ __forceinline__ float flog2(float x) { return __builtin_amdgcn_logf(x); }

template <int CTRL>
__device__ __forceinline__ int dpp_i(int x) {
    return __builtin_amdgcn_update_dpp(x, x, CTRL, 0xF, 0xF, false);
}
// whole-wave rotate: lane i receives lane (i-1)&63
__device__ __forceinline__ float ror1_f(float x) {
    return __int_as_float(dpp_i<0x13C>(__float_as_int(x)));
}
__device__ __forceinline__ int ror1_i(int x) { return dpp_i<0x13C>(x); }

__device__ __forceinline__ float fldexp(float x, int n) {
#if __has_builtin(__builtin_amdgcn_ldexpf)
    return __builtin_amdgcn_ldexpf(x, n);
#else
    return ldexpf(x, n);
#endif
}
// frexp-style exponent; 0 for x==0
__device__ __forceinline__ int fexp_of(float x) {
#if __has_builtin(__builtin_amdgcn_frexp_expf)
    return __builtin_amdgcn_frexp_expf(x);
#else
    const int bx = (__float_as_int(x) >> 23) & 0xFF;
    return (x > 0.0f) ? (bx - 126) : 0;
#endif
}

// global -> LDS direct copy, 16 B/lane (1 KB/instr). LDS dest is the
// wave-uniform base; HW lands lane i at base + i*16.
typedef const __attribute__((address_space(1))) void gas_void;
typedef __attribute__((address_space(3))) void las_void;
__device__ __forceinline__ void g2l16(const float* g, float* l) {
    __builtin_amdgcn_global_load_lds((gas_void*)g, (las_void*)l, 16, 0, 0);
}
__device__ __forceinline__ void g2l4(const float* g, float* l) {
    __builtin_amdgcn_global_load_lds((gas_void*)g, (las_void*)l, 4, 0, 0);
}

// One DP step (verified math from rounds 6/7): linear recursion on f32
// mantissas with per-lane int exponent e; dead lanes adopt the neighbor's
// exponent so the DP front is never flushed; ldexp(0,n)=0 keeps lane-0
// wraparound garbage out of live arithmetic (prevE cndmask'd, sk gated).
#define LSTEP(pL, pB)                                                         \
    {                                                                         \
        const float pBe = (pB) + EPS_;                                        \
        const float pLe = (pL) + EPS_;                                        \
        const int   ep  = ror1_i(e);                                          \
        const float mpE = ror1_f(aE);                                         \
        const float mpO = ror1_f(aO);                                         \
        const bool dead = (fmaxf(aE, aO) == 0.0f);                            \
        e = dead ? ep : e;                                                    \
        const int   d   = ep - e;                                             \
        float prevE = fldexp(mpE, d);                                         \
        const float prevO = fldexp(mpO, d);                                   \
        prevE = isL0 ? fldexp(a0, e0 - e) : prevE;                            \
        const float sk = can_skip ? prevO : 0.0f;                             \
        const float nE = (aE + aO) * pBe;                                     \
        const float nO = (aO + prevE + sk) * pLe;                             \
        a0 *= pBe;                                                            \
        aE = nE; aO = nO;                                                     \
    }

// Renorm every 4 steps (shrink >= pmin^4 = 2^-68: no underflow; growth <=
// 6^4: no overflow). frexp_exp(0)=0 so dead lanes are a no-op.
#define RENORM4                                                               \
    {                                                                         \
        const int x = fexp_of(fmaxf(aE, aO));                                 \
        aE = fldexp(aE, -x); aO = fldexp(aO, -x); e += x;                     \
        const int x0 = fexp_of(a0);                                           \
        a0 = fldexp(a0, -x0); e0 += x0;                                       \
    }

__global__ __launch_bounds__(64, 1)
void ctc_fwd(const int* __restrict__ yt, const float* __restrict__ yp,
             float* __restrict__ out) {
    __shared__ float sm[2 * LDSF];                // 32 KB, double buffer

    const int b    = blockIdx.x;
    const int lane = threadIdx.x;                 // 0..63
    const int lab  = yt[b * L_ + lane];           // label of state 2*lane+1
    const int labp = __shfl_up(lab, 1);           // init-only, off hot path
    const bool can_skip = (lane > 0) && (lab != labp);
    const bool isL0     = (lane == 0);

    const float* __restrict__ base = yp + (size_t)b * T_ * C_;

    // ---- stage rows 1..32 into buffer 0 (16 x 1KB) ----
    {
        const float* src = base + C_;
#pragma unroll
        for (int j = 0; j < 16; ++j)
            g2l16(src + j * 256 + lane * 4, sm + j * 256);
    }

    // ---- t=0 init (linear, exponent 0): only states 0 and 1 reachable ----
    float a0 = base[BLANK_] + EPS_;               // state 0 (uniform)
    float aO = isL0 ? (base[lab] + EPS_) : 0.0f;  // state 2i+1
    float aE = 0.0f;                              // state 2i+2
    int   e  = 0, e0 = 0;

    // buffer 0 ready; also drains the init loads.
    asm volatile("s_waitcnt vmcnt(0)" ::: "memory");

    // ---- register ring: rows t=1..4 (buf0 rows 0..3) ----
    float rL[4], rB[4];
#pragma unroll
    for (int j = 0; j < 4; ++j) {
        rL[j] = sm[j * C_ + lab];
        rB[j] = sm[j * C_ + BLANK_];
    }

    // ---- 31 full chunks: t = 1+32c .. 32+32c (rows 1..992) ----
#pragma unroll 1
    for (int c = 0; c < 31; ++c) {
        const int bc = (c & 1) * LDSF;            // current buffer
        const int bo = LDSF - bc;                 // other buffer
        // stage next chunk: rows 33+32c .. ; c==30 stages the final 31 rows
        {
            const float* src = base + (size_t)(33 + 32 * c) * C_;
            const int nKB = (c == 30) ? 15 : 16;
            for (int j = 0; j < nKB; ++j)
                g2l16(src + j * 256 + lane * 4, sm + bo + j * 256);
            if (c == 30) {                        // row 1023: 512 B via 2x4B
                const float* s2 = src + 15 * 256;
                g2l4(s2 + lane,      sm + bo + 15 * 256);
                g2l4(s2 + 64 + lane, sm + bo + 15 * 256 + 64);
            }
        }
        // steps 0..27: prefetch k+4 from current buffer
#pragma unroll
        for (int k = 0; k < 28; ++k) {
            const float pL = rL[k & 3];
            const float pB = rB[k & 3];
            rL[k & 3] = sm[bc + (k + 4) * C_ + lab];
            rB[k & 3] = sm[bc + (k + 4) * C_ + BLANK_];
            LSTEP(pL, pB)
            if ((k & 3) == 3) RENORM4
        }
        // next buffer guaranteed staged (issued ~28 steps ago)
        asm volatile("s_waitcnt vmcnt(0)" ::: "memory");
        // steps 28..31: prefetch rows 0..3 of the other buffer
#pragma unroll
        for (int k = 28; k < 32; ++k) {
            const float pL = rL[k & 3];
            const float pB = rB[k & 3];
            rL[k & 3] = sm[bo + (k - 28) * C_ + lab];
            rB[k & 3] = sm[bo + (k - 28) * C_ + BLANK_];
            LSTEP(pL, pB)
            if ((k & 3) == 3) RENORM4
        }
    }

    // ---- final chunk: t = 993..1023 (31 rows) in buffer 1 ----
    {
        const int fb = LDSF;
#pragma unroll
        for (int k = 0; k < 31; ++k) {
            const float pL = rL[k & 3];
            const float pB = rB[k & 3];
            if (k < 27) {
                rL[k & 3] = sm[fb + (k + 4) * C_ + lab];
                rB[k & 3] = sm[fb + (k + 4) * C_ + BLANK_];
            }
            LSTEP(pL, pB)
            if ((k & 3) == 3) RENORM4
        }
    }

    // loss = -ln(alpha[127] + alpha[128]); both live in lane 63 at scale 2^e.
    if (lane == 63) {
        const float s = aE + aO;                  // in [2^-70, 8): v_log safe
        out[b] = -(flog2(s) + (float)e) * LN2_;
    }
}

extern "C" void kernel_launch(void* const* d_in, const int* in_sizes, int n_in,
                              void* d_out, int out_size, void* d_ws, size_t ws_size,
                              hipStream_t stream) {
    const int*   y_true = (const int*)d_in[0];
    const float* y_pred = (const float*)d_in[1];
    float*       out    = (float*)d_out;
    ctc_fwd<<<B_, 64, 0, stream>>>(y_true, y_pred, out);
}